// Round 12
// baseline (306.030 us; speedup 1.0000x reference)
//
#include <hip/hip_runtime.h>

#define NPTS 131072
#define HTBL 262147

// h < 2^38.  2^18 = 262144 == -3 (mod 262147).  Two folds + one conditional add.
__device__ __forceinline__ unsigned int mod_tbl(unsigned long long h) {
    int r = (int)((unsigned int)h & 0x3FFFFu) - 3 * (int)(unsigned int)(h >> 18) + 3145764; // r in [36, 3407907]
    int s = (r & 0x3FFFF) - 3 * (r >> 18);                                                  // s in [-39, 262143]
    return (unsigned int)(s < 0 ? s + HTBL : s);
}

__global__ __launch_bounds__(256) void embed_kernel(
    const float4* __restrict__ xyz,
    const float2* __restrict__ dense,
    const float2* __restrict__ hasht,
    const float*  __restrict__ bounds,
    float* __restrict__ out)
{
    const int NUMS[16] = {16,22,30,42,58,80,110,152,210,290,400,553,763,1053,1453,2005};
    // f32-rounded ENTRIES_SIZE (module constant is (1/(num-1)).astype(float32))
    const float SIZES[16] = {
        (float)(1.0/15.0),  (float)(1.0/21.0),  (float)(1.0/29.0),  (float)(1.0/41.0),
        (float)(1.0/57.0),  (float)(1.0/79.0),  (float)(1.0/109.0), (float)(1.0/151.0),
        (float)(1.0/209.0), (float)(1.0/289.0), (float)(1.0/399.0), (float)(1.0/552.0),
        (float)(1.0/762.0), (float)(1.0/1052.0),(float)(1.0/1452.0),(float)(1.0/2004.0)};

    int tid = blockIdx.x * 256 + threadIdx.x;
    int n = tid >> 4;
    int l = tid & 15;

    float4 p = xyz[n];
    float b00 = bounds[0], b01 = bounds[1], b02 = bounds[2], b03 = bounds[3];
    float b10 = bounds[4], b11 = bounds[5], b12 = bounds[6], b13 = bounds[7];

    // x-stage (confirmed at P_A by r9/r10/r11): recip-multiply in f32.
    float i0 = 1.0f / (b10 - b00);
    float i1 = 1.0f / (b11 - b01);
    float i2 = 1.0f / (b12 - b02);
    float i3 = 1.0f / (b13 - b03);
    float x0 = (p.x - b00) * i0;
    float x1 = (p.y - b01) * i1;
    float x2 = (p.z - b02) * i2;
    float x3 = (p.w - b03) * i3;

    // flt-stage (C2): reciprocal-multiply of the SIZE division too:
    //   inv_size = RN32(1.0f / size32)  (size32 = f32 ENTRIES_SIZE)
    //   flt = RN32(x * inv_size)
    // Note RN32(1/RN32(1/(n-1))) != (n-1) exactly — a distinct multiplier vs r10/r11.
    int   nm1 = NUMS[l] - 1;
    float invsz = 1.0f / SIZES[l];
    float f0 = x0 * invsz, f1 = x1 * invsz, f2 = x2 * invsz, f3 = x3 * invsz;

    // corner = int(flt + offs) f32, then clip; offs is 0.0f or 1.0f
    int c0a = min(max((int)f0, 0), nm1), c0b = min(max((int)(f0 + 1.0f), 0), nm1);
    int c1a = min(max((int)f1, 0), nm1), c1b = min(max((int)(f1 + 1.0f), 0), nm1);
    int c2a = min(max((int)f2, 0), nm1), c2b = min(max((int)(f2 + 1.0f), 0), nm1);
    int c3a = min(max((int)f3, 0), nm1), c3b = min(max((int)(f3 + 1.0f), 0), nm1);

    float o0 = f0 - (float)c0a;
    float o1 = f1 - (float)c1a;
    float o2 = f2 - (float)c2a;
    float o3 = f3 - (float)c3a;

    unsigned int idx[16];
    const float2* tbl;
    if (l >= 2) {
        tbl = hasht + (size_t)(l - 2) * HTBL;
        unsigned long long a0 = (unsigned long long)(unsigned int)c0a;
        unsigned long long b0 = (unsigned long long)(unsigned int)c0b;
        unsigned long long a1 = (unsigned long long)(unsigned int)c1a * 19349663ull;
        unsigned long long b1 = (unsigned long long)(unsigned int)c1b * 19349663ull;
        unsigned long long a2 = (unsigned long long)(unsigned int)c2a * 51471207ull;
        unsigned long long b2 = (unsigned long long)(unsigned int)c2b * 51471207ull;
        unsigned long long a3 = (unsigned long long)(unsigned int)c3a * 83492791ull;
        unsigned long long b3 = (unsigned long long)(unsigned int)c3b * 83492791ull;
        #pragma unroll
        for (int c = 0; c < 16; ++c) {
            unsigned long long h = ((c & 1) ? b0 : a0) ^ ((c & 2) ? b1 : a1)
                                 ^ ((c & 4) ? b2 : a2) ^ ((c & 8) ? b3 : a3);
            idx[c] = mod_tbl(h);
        }
    } else {
        tbl = dense + (l == 0 ? 0 : 65536);
        int s3 = nm1 + 1, s2 = s3 * s3, s1 = s2 * s3;
        int d0a = c0a * s1, d0b = c0b * s1;
        int d1a = c1a * s2, d1b = c1b * s2;
        int d2a = c2a * s3, d2b = c2b * s3;
        #pragma unroll
        for (int c = 0; c < 16; ++c) {
            idx[c] = (unsigned int)(((c & 1) ? d0b : d0a) + ((c & 2) ? d1b : d1a)
                                  + ((c & 4) ? d2b : d2a) + ((c & 8) ? c3b : c3a));
        }
    }

    // issue all 16 gathers, then consume (ILP for latency hiding)
    float2 v[16];
    #pragma unroll
    for (int c = 0; c < 16; ++c) v[c] = tbl[idx[c]];

    // weights/accumulation in f64 (continuous path: rounding diffs ~1e-9 << threshold)
    double O0 = o0, O1 = o1, O2 = o2, O3 = o3;
    double w0a = 1.0 - O0, w1a = 1.0 - O1, w2a = 1.0 - O2, w3a = 1.0 - O3;
    double w01[4] = { w0a * w1a, O0 * w1a, w0a * O1, O0 * O1 };
    double acc_i = 0.0, acc_a = 0.0, acc_b = 0.0;
    #pragma unroll
    for (int c = 0; c < 16; ++c) {
        double tri = w01[c & 3] * ((c & 4) ? O2 : w2a);
        double s   = (double)v[c].x + (double)v[c].y;
        double ts  = tri * s;
        acc_i += ts * ((c & 8) ? O3 : w3a);
        if (c & 8) acc_b += ts; else acc_a += ts;
    }

    out[n * 16 + l] = (float)acc_i;          // interp (N,16)
    float* sm = out + NPTS * 16;             // smooth_t (N,32) = [ta | tb]
    sm[n * 32 + l]      = (float)acc_a;
    sm[n * 32 + 16 + l] = (float)acc_b;
}

extern "C" void kernel_launch(void* const* d_in, const int* in_sizes, int n_in,
                              void* d_out, int out_size, void* d_ws, size_t ws_size,
                              hipStream_t stream) {
    const float4* xyz    = (const float4*)d_in[0];
    const float2* dense  = (const float2*)d_in[1];
    const float2* hasht  = (const float2*)d_in[2];
    const float*  bounds = (const float*)d_in[3];
    float* out = (float*)d_out;
    embed_kernel<<<dim3((NPTS * 16) / 256), dim3(256), 0, stream>>>(xyz, dense, hasht, bounds, out);
}

// Round 13
// 141.286 us; speedup vs baseline: 2.1660x; 2.1660x over previous
//
#include <hip/hip_runtime.h>

#define NPTS 131072
#define HTBL 262147

// h < 2^38.  2^18 = 262144 == -3 (mod 262147).  Two folds + one conditional add.
__device__ __forceinline__ unsigned int mod_tbl(unsigned long long h) {
    int r = (int)((unsigned int)h & 0x3FFFFu) - 3 * (int)(unsigned int)(h >> 18) + 3145764;
    int s = (r & 0x3FFFF) - 3 * (r >> 18);
    return (unsigned int)(s < 0 ? s + HTBL : s);
}

__device__ __forceinline__ void compute_point_level(
    float4 p, const float* bounds, int l,
    float& acc_i, float& acc_a, float& acc_b,
    const float2* __restrict__ dense, const float2* __restrict__ hasht)
{
    const int NUMS[16] = {16,22,30,42,58,80,110,152,210,290,400,553,763,1053,1453,2005};
    const float SIZES[16] = {
        (float)(1.0/15.0),  (float)(1.0/21.0),  (float)(1.0/29.0),  (float)(1.0/41.0),
        (float)(1.0/57.0),  (float)(1.0/79.0),  (float)(1.0/109.0), (float)(1.0/151.0),
        (float)(1.0/209.0), (float)(1.0/289.0), (float)(1.0/399.0), (float)(1.0/552.0),
        (float)(1.0/762.0), (float)(1.0/1052.0),(float)(1.0/1452.0),(float)(1.0/2004.0)};

    float b00 = bounds[0], b01 = bounds[1], b02 = bounds[2], b03 = bounds[3];
    float b10 = bounds[4], b11 = bounds[5], b12 = bounds[6], b13 = bounds[7];

    // verified chain: recip-mult x (f32), recip-mult size (f32)
    float x0 = (p.x - b00) * (1.0f / (b10 - b00));
    float x1 = (p.y - b01) * (1.0f / (b11 - b01));
    float x2 = (p.z - b02) * (1.0f / (b12 - b02));
    float x3 = (p.w - b03) * (1.0f / (b13 - b13 + (b13 - b03)));  // placeholder replaced below

    // (the above line is wrong-looking; recompute x3 correctly)
    x3 = (p.w - b03) * (1.0f / (b13 - b03));

    int   nm1 = NUMS[l] - 1;
    float invsz = 1.0f / SIZES[l];
    float f0 = x0 * invsz, f1 = x1 * invsz, f2 = x2 * invsz, f3 = x3 * invsz;

    int c0a = min(max((int)f0, 0), nm1), c0b = min(max((int)(f0 + 1.0f), 0), nm1);
    int c1a = min(max((int)f1, 0), nm1), c1b = min(max((int)(f1 + 1.0f), 0), nm1);
    int c2a = min(max((int)f2, 0), nm1), c2b = min(max((int)(f2 + 1.0f), 0), nm1);
    int c3a = min(max((int)f3, 0), nm1), c3b = min(max((int)(f3 + 1.0f), 0), nm1);

    float o0 = f0 - (float)c0a;
    float o1 = f1 - (float)c1a;
    float o2 = f2 - (float)c2a;
    float o3 = f3 - (float)c3a;

    unsigned int idx[16];
    const float2* tbl;
    if (l >= 2) {
        tbl = hasht + (size_t)(l - 2) * HTBL;
        unsigned long long a0 = (unsigned long long)(unsigned int)c0a;
        unsigned long long b0 = (unsigned long long)(unsigned int)c0b;
        unsigned long long a1 = (unsigned long long)(unsigned int)c1a * 19349663ull;
        unsigned long long b1 = (unsigned long long)(unsigned int)c1b * 19349663ull;
        unsigned long long a2 = (unsigned long long)(unsigned int)c2a * 51471207ull;
        unsigned long long b2 = (unsigned long long)(unsigned int)c2b * 51471207ull;
        unsigned long long a3 = (unsigned long long)(unsigned int)c3a * 83492791ull;
        unsigned long long b3 = (unsigned long long)(unsigned int)c3b * 83492791ull;
        #pragma unroll
        for (int c = 0; c < 16; ++c) {
            unsigned long long h = ((c & 1) ? b0 : a0) ^ ((c & 2) ? b1 : a1)
                                 ^ ((c & 4) ? b2 : a2) ^ ((c & 8) ? b3 : a3);
            idx[c] = mod_tbl(h);
        }
    } else {
        tbl = dense + (l == 0 ? 0 : 65536);
        int s3 = nm1 + 1, s2 = s3 * s3, s1 = s2 * s3;
        int d0a = c0a * s1, d0b = c0b * s1;
        int d1a = c1a * s2, d1b = c1b * s2;
        int d2a = c2a * s3, d2b = c2b * s3;
        #pragma unroll
        for (int c = 0; c < 16; ++c) {
            idx[c] = (unsigned int)(((c & 1) ? d0b : d0a) + ((c & 2) ? d1b : d1a)
                                  + ((c & 4) ? d2b : d2a) + ((c & 8) ? c3b : c3a));
        }
    }

    float2 v[16];
    #pragma unroll
    for (int c = 0; c < 16; ++c) v[c] = tbl[idx[c]];

    double O0 = o0, O1 = o1, O2 = o2, O3 = o3;
    double w0a = 1.0 - O0, w1a = 1.0 - O1, w2a = 1.0 - O2, w3a = 1.0 - O3;
    double w01[4] = { w0a * w1a, O0 * w1a, w0a * O1, O0 * O1 };
    double ai = 0.0, aa = 0.0, ab = 0.0;
    #pragma unroll
    for (int c = 0; c < 16; ++c) {
        double tri = w01[c & 3] * ((c & 4) ? O2 : w2a);
        double s   = (double)v[c].x + (double)v[c].y;
        double ts  = tri * s;
        ai += ts * ((c & 8) ? O3 : w3a);
        if (c & 8) ab += ts; else aa += ts;
    }
    acc_i = (float)ai; acc_a = (float)aa; acc_b = (float)ab;
}

// Pass 1: one level per block; blockIdx = chunk*16 + level  =>  level l lands on
// XCD (l & 7) under round-robin dispatch => per-XCD table working set ~4.2 MB ~ L2.
// Writes level-major (coalesced) into workspace.
__global__ __launch_bounds__(256) void gather_kernel(
    const float4* __restrict__ xyz,
    const float2* __restrict__ dense,
    const float2* __restrict__ hasht,
    const float*  __restrict__ bounds,
    float* __restrict__ wsI, float* __restrict__ wsA, float* __restrict__ wsB)
{
    int b = blockIdx.x;
    int l = b & 15;
    int n = ((b >> 4) << 8) + threadIdx.x;
    float4 p = xyz[n];
    float ai, aa, ab;
    compute_point_level(p, bounds, l, ai, aa, ab, dense, hasht);
    wsI[l * NPTS + n] = ai;
    wsA[l * NPTS + n] = aa;
    wsB[l * NPTS + n] = ab;
}

// Pass 2: transpose level-major ws -> row-major out via LDS tiles (64 points/block).
__global__ __launch_bounds__(256) void transpose_kernel(
    const float* __restrict__ wsI, const float* __restrict__ wsA,
    const float* __restrict__ wsB, float* __restrict__ out)
{
    __shared__ float tI[16][65], tA[16][65], tB[16][65];
    int t = threadIdx.x;
    int n0 = blockIdx.x * 64;
    #pragma unroll
    for (int k = 0; k < 4; ++k) {
        int l = k * 4 + (t >> 6);
        int pp = t & 63;
        tI[l][pp] = wsI[l * NPTS + n0 + pp];
        tA[l][pp] = wsA[l * NPTS + n0 + pp];
        tB[l][pp] = wsB[l * NPTS + n0 + pp];
    }
    __syncthreads();
    // interp rows: (N,16) -> 64 rows * 4 float4
    {
        int pp = t >> 2, q = t & 3;
        float4 v = make_float4(tI[q*4+0][pp], tI[q*4+1][pp], tI[q*4+2][pp], tI[q*4+3][pp]);
        ((float4*)out)[(size_t)(n0 + pp) * 4 + q] = v;
    }
    // smooth rows: (N,32) = [ta|tb] -> 64 rows * 8 float4
    float4* sm4 = (float4*)(out + (size_t)NPTS * 16);
    #pragma unroll
    for (int j = 0; j < 2; ++j) {
        int idx = j * 256 + t;
        int pp = idx >> 3, q = idx & 7;
        float4 v;
        if (q < 4) v = make_float4(tA[q*4+0][pp], tA[q*4+1][pp], tA[q*4+2][pp], tA[q*4+3][pp]);
        else { int qq = q - 4; v = make_float4(tB[qq*4+0][pp], tB[qq*4+1][pp], tB[qq*4+2][pp], tB[qq*4+3][pp]); }
        sm4[(size_t)(n0 + pp) * 8 + q] = v;
    }
}

// Fallback single-kernel (r12, passing): direct row-major writes.
__global__ __launch_bounds__(256) void embed_kernel(
    const float4* __restrict__ xyz,
    const float2* __restrict__ dense,
    const float2* __restrict__ hasht,
    const float*  __restrict__ bounds,
    float* __restrict__ out)
{
    int tid = blockIdx.x * 256 + threadIdx.x;
    int n = tid >> 4;
    int l = tid & 15;
    float4 p = xyz[n];
    float ai, aa, ab;
    compute_point_level(p, bounds, l, ai, aa, ab, dense, hasht);
    out[n * 16 + l] = ai;
    float* sm = out + NPTS * 16;
    sm[n * 32 + l]      = aa;
    sm[n * 32 + 16 + l] = ab;
}

extern "C" void kernel_launch(void* const* d_in, const int* in_sizes, int n_in,
                              void* d_out, int out_size, void* d_ws, size_t ws_size,
                              hipStream_t stream) {
    const float4* xyz    = (const float4*)d_in[0];
    const float2* dense  = (const float2*)d_in[1];
    const float2* hasht  = (const float2*)d_in[2];
    const float*  bounds = (const float*)d_in[3];
    float* out = (float*)d_out;

    const size_t plane = (size_t)16 * NPTS;           // floats per ws plane
    if (ws_size >= 3 * plane * sizeof(float)) {
        float* wsI = (float*)d_ws;
        float* wsA = wsI + plane;
        float* wsB = wsA + plane;
        gather_kernel<<<dim3(8192), dim3(256), 0, stream>>>(xyz, dense, hasht, bounds, wsI, wsA, wsB);
        transpose_kernel<<<dim3(NPTS / 64), dim3(256), 0, stream>>>(wsI, wsA, wsB, out);
    } else {
        embed_kernel<<<dim3((NPTS * 16) / 256), dim3(256), 0, stream>>>(xyz, dense, hasht, bounds, out);
    }
}

// Round 14
// 124.213 us; speedup vs baseline: 2.4638x; 1.1375x over previous
//
#include <hip/hip_runtime.h>

#define NPTS 131072
#define HTBL 262147

// h < 2^38.  2^18 = 262144 == -3 (mod 262147).  Two folds + one conditional add.
__device__ __forceinline__ unsigned int mod_tbl(unsigned long long h) {
    int r = (int)((unsigned int)h & 0x3FFFFu) - 3 * (int)(unsigned int)(h >> 18) + 3145764;
    int s = (r & 0x3FFFF) - 3 * (r >> 18);
    return (unsigned int)(s < 0 ? s + HTBL : s);
}

__device__ __forceinline__ void compute_point_level(
    float4 p, const float* bounds, int l,
    float& acc_i, float& acc_a, float& acc_b,
    const float2* __restrict__ dense, const float2* __restrict__ hasht)
{
    const int NUMS[16] = {16,22,30,42,58,80,110,152,210,290,400,553,763,1053,1453,2005};
    const float SIZES[16] = {
        (float)(1.0/15.0),  (float)(1.0/21.0),  (float)(1.0/29.0),  (float)(1.0/41.0),
        (float)(1.0/57.0),  (float)(1.0/79.0),  (float)(1.0/109.0), (float)(1.0/151.0),
        (float)(1.0/209.0), (float)(1.0/289.0), (float)(1.0/399.0), (float)(1.0/552.0),
        (float)(1.0/762.0), (float)(1.0/1052.0),(float)(1.0/1452.0),(float)(1.0/2004.0)};

    float b00 = bounds[0], b01 = bounds[1], b02 = bounds[2], b03 = bounds[3];
    float b10 = bounds[4], b11 = bounds[5], b12 = bounds[6], b13 = bounds[7];

    // verified chain: recip-mult x (f32), recip-mult size (f32)
    float x0 = (p.x - b00) * (1.0f / (b10 - b00));
    float x1 = (p.y - b01) * (1.0f / (b11 - b01));
    float x2 = (p.z - b02) * (1.0f / (b12 - b02));
    float x3 = (p.w - b03) * (1.0f / (b13 - b03));

    int   nm1 = NUMS[l] - 1;
    float invsz = 1.0f / SIZES[l];
    float f0 = x0 * invsz, f1 = x1 * invsz, f2 = x2 * invsz, f3 = x3 * invsz;

    int c0a = min(max((int)f0, 0), nm1), c0b = min(max((int)(f0 + 1.0f), 0), nm1);
    int c1a = min(max((int)f1, 0), nm1), c1b = min(max((int)(f1 + 1.0f), 0), nm1);
    int c2a = min(max((int)f2, 0), nm1), c2b = min(max((int)(f2 + 1.0f), 0), nm1);
    int c3a = min(max((int)f3, 0), nm1), c3b = min(max((int)(f3 + 1.0f), 0), nm1);

    float o0 = f0 - (float)c0a;
    float o1 = f1 - (float)c1a;
    float o2 = f2 - (float)c2a;
    float o3 = f3 - (float)c3a;

    float2 v[16];
    if (l >= 2) {
        const float2* tbl = hasht + (size_t)(l - 2) * HTBL;
        unsigned long long a0 = (unsigned long long)(unsigned int)c0a;
        unsigned long long b0 = (unsigned long long)(unsigned int)c0b;
        unsigned long long t1a = (unsigned long long)(unsigned int)c1a * 19349663ull;
        unsigned long long t1b = (unsigned long long)(unsigned int)c1b * 19349663ull;
        unsigned long long t2a = (unsigned long long)(unsigned int)c2a * 51471207ull;
        unsigned long long t2b = (unsigned long long)(unsigned int)c2b * 51471207ull;
        unsigned long long t3a = (unsigned long long)(unsigned int)c3a * 83492791ull;
        unsigned long long t3b = (unsigned long long)(unsigned int)c3b * 83492791ull;
        bool pair_adj = (c0b == c0a + 1) && !(c0a & 1);   // h_b = h_a ^ 1, slots {e,e+1}
        bool pair_same = (c0b == c0a);
        #pragma unroll
        for (int k = 0; k < 8; ++k) {
            unsigned long long R = ((k & 1) ? t1b : t1a) ^ ((k & 2) ? t2b : t2a)
                                 ^ ((k & 4) ? t3b : t3a);
            unsigned long long ha = a0 ^ R;
            float2 va, vb;
            if (pair_same) {
                va = tbl[mod_tbl(ha)];
                vb = va;
            } else if (pair_adj) {
                unsigned int m = mod_tbl(ha & ~1ull);       // slot of even member
                bool a_even = !(ha & 1);
                if (m != HTBL - 1 && !(m & 1)) {
                    float4 q = *reinterpret_cast<const float4*>(tbl + m); // 16B aligned
                    va = a_even ? make_float2(q.x, q.y) : make_float2(q.z, q.w);
                    vb = a_even ? make_float2(q.z, q.w) : make_float2(q.x, q.y);
                } else if (m != HTBL - 1) {
                    float2 qa = tbl[m], qb = tbl[m + 1];    // same line unless m%8==7
                    va = a_even ? qa : qb;
                    vb = a_even ? qb : qa;
                } else {                                    // wrap TBL-1 -> 0
                    va = tbl[a_even ? m : 0];
                    vb = tbl[a_even ? 0 : m];
                }
            } else {
                unsigned long long hb = b0 ^ R;
                va = tbl[mod_tbl(ha)];
                vb = tbl[mod_tbl(hb)];
            }
            v[2 * k]     = va;
            v[2 * k + 1] = vb;
        }
    } else {
        const float2* tbl = dense + (l == 0 ? 0 : 65536);
        int s3 = nm1 + 1, s2 = s3 * s3, s1 = s2 * s3;
        int d0a = c0a * s1, d0b = c0b * s1;
        int d1a = c1a * s2, d1b = c1b * s2;
        int d2a = c2a * s3, d2b = c2b * s3;
        bool adj = (c3b == c3a + 1);
        #pragma unroll
        for (int c = 0; c < 8; ++c) {    // pairs (c, c+8) over dim3: idx, idx+1
            int base = ((c & 1) ? d0b : d0a) + ((c & 2) ? d1b : d1a)
                     + ((c & 4) ? d2b : d2a) + c3a;
            float2 va, vb;
            if (!adj) {
                va = tbl[base]; vb = va;                    // clipped: same slot
            } else if (!(base & 1)) {
                float4 q = *reinterpret_cast<const float4*>(tbl + base);
                va = make_float2(q.x, q.y); vb = make_float2(q.z, q.w);
            } else {
                va = tbl[base]; vb = tbl[base + 1];
            }
            v[c]     = va;
            v[c + 8] = vb;
        }
    }

    double O0 = o0, O1 = o1, O2 = o2, O3 = o3;
    double w0a = 1.0 - O0, w1a = 1.0 - O1, w2a = 1.0 - O2, w3a = 1.0 - O3;
    double w01[4] = { w0a * w1a, O0 * w1a, w0a * O1, O0 * O1 };
    double ai = 0.0, aa = 0.0, ab = 0.0;
    #pragma unroll
    for (int c = 0; c < 16; ++c) {
        double tri = w01[c & 3] * ((c & 4) ? O2 : w2a);
        double s   = (double)v[c].x + (double)v[c].y;
        double ts  = tri * s;
        ai += ts * ((c & 8) ? O3 : w3a);
        if (c & 8) ab += ts; else aa += ts;
    }
    acc_i = (float)ai; acc_a = (float)aa; acc_b = (float)ab;
}

// Pass 1: one level per block; blockIdx = chunk*16 + level => level l on XCD (l&7)
// under round-robin dispatch => per-XCD table working set ~4.2 MB ~ L2.
__global__ __launch_bounds__(256) void gather_kernel(
    const float4* __restrict__ xyz,
    const float2* __restrict__ dense,
    const float2* __restrict__ hasht,
    const float*  __restrict__ bounds,
    float* __restrict__ wsI, float* __restrict__ wsA, float* __restrict__ wsB)
{
    int b = blockIdx.x;
    int l = b & 15;
    int n = ((b >> 4) << 8) + threadIdx.x;
    float4 p = xyz[n];
    float ai, aa, ab;
    compute_point_level(p, bounds, l, ai, aa, ab, dense, hasht);
    wsI[l * NPTS + n] = ai;
    wsA[l * NPTS + n] = aa;
    wsB[l * NPTS + n] = ab;
}

// Pass 2: transpose level-major ws -> row-major out via LDS tiles (64 points/block).
__global__ __launch_bounds__(256) void transpose_kernel(
    const float* __restrict__ wsI, const float* __restrict__ wsA,
    const float* __restrict__ wsB, float* __restrict__ out)
{
    __shared__ float tI[16][65], tA[16][65], tB[16][65];
    int t = threadIdx.x;
    int n0 = blockIdx.x * 64;
    #pragma unroll
    for (int k = 0; k < 4; ++k) {
        int l = k * 4 + (t >> 6);
        int pp = t & 63;
        tI[l][pp] = wsI[l * NPTS + n0 + pp];
        tA[l][pp] = wsA[l * NPTS + n0 + pp];
        tB[l][pp] = wsB[l * NPTS + n0 + pp];
    }
    __syncthreads();
    {
        int pp = t >> 2, q = t & 3;
        float4 v = make_float4(tI[q*4+0][pp], tI[q*4+1][pp], tI[q*4+2][pp], tI[q*4+3][pp]);
        ((float4*)out)[(size_t)(n0 + pp) * 4 + q] = v;
    }
    float4* sm4 = (float4*)(out + (size_t)NPTS * 16);
    #pragma unroll
    for (int j = 0; j < 2; ++j) {
        int idx = j * 256 + t;
        int pp = idx >> 3, q = idx & 7;
        float4 v;
        if (q < 4) v = make_float4(tA[q*4+0][pp], tA[q*4+1][pp], tA[q*4+2][pp], tA[q*4+3][pp]);
        else { int qq = q - 4; v = make_float4(tB[qq*4+0][pp], tB[qq*4+1][pp], tB[qq*4+2][pp], tB[qq*4+3][pp]); }
        sm4[(size_t)(n0 + pp) * 8 + q] = v;
    }
}

// Fallback single-kernel: direct row-major writes.
__global__ __launch_bounds__(256) void embed_kernel(
    const float4* __restrict__ xyz,
    const float2* __restrict__ dense,
    const float2* __restrict__ hasht,
    const float*  __restrict__ bounds,
    float* __restrict__ out)
{
    int tid = blockIdx.x * 256 + threadIdx.x;
    int n = tid >> 4;
    int l = tid & 15;
    float4 p = xyz[n];
    float ai, aa, ab;
    compute_point_level(p, bounds, l, ai, aa, ab, dense, hasht);
    out[n * 16 + l] = ai;
    float* sm = out + NPTS * 16;
    sm[n * 32 + l]      = aa;
    sm[n * 32 + 16 + l] = ab;
}

extern "C" void kernel_launch(void* const* d_in, const int* in_sizes, int n_in,
                              void* d_out, int out_size, void* d_ws, size_t ws_size,
                              hipStream_t stream) {
    const float4* xyz    = (const float4*)d_in[0];
    const float2* dense  = (const float2*)d_in[1];
    const float2* hasht  = (const float2*)d_in[2];
    const float*  bounds = (const float*)d_in[3];
    float* out = (float*)d_out;

    const size_t plane = (size_t)16 * NPTS;
    if (ws_size >= 3 * plane * sizeof(float)) {
        float* wsI = (float*)d_ws;
        float* wsA = wsI + plane;
        float* wsB = wsA + plane;
        gather_kernel<<<dim3(8192), dim3(256), 0, stream>>>(xyz, dense, hasht, bounds, wsI, wsA, wsB);
        transpose_kernel<<<dim3(NPTS / 64), dim3(256), 0, stream>>>(wsI, wsA, wsB, out);
    } else {
        embed_kernel<<<dim3((NPTS * 16) / 256), dim3(256), 0, stream>>>(xyz, dense, hasht, bounds, out);
    }
}

// Round 15
// 109.175 us; speedup vs baseline: 2.8031x; 1.1377x over previous
//
#include <hip/hip_runtime.h>

#define NPTS 131072
#define HTBL 262147

// h < 2^38.  2^18 = 262144 == -3 (mod 262147).  Two folds + one conditional add.
__device__ __forceinline__ unsigned int mod_tbl(unsigned long long h) {
    int r = (int)((unsigned int)h & 0x3FFFFu) - 3 * (int)(unsigned int)(h >> 18) + 3145764;
    int s = (r & 0x3FFFF) - 3 * (r >> 18);
    return (unsigned int)(s < 0 ? s + HTBL : s);
}

__device__ __forceinline__ void compute_point_level(
    float4 p, const float* bounds, int l,
    float& acc_i, float& acc_a, float& acc_b,
    const float2* __restrict__ dense, const float2* __restrict__ hasht)
{
    const int NUMS[16] = {16,22,30,42,58,80,110,152,210,290,400,553,763,1053,1453,2005};
    const float SIZES[16] = {
        (float)(1.0/15.0),  (float)(1.0/21.0),  (float)(1.0/29.0),  (float)(1.0/41.0),
        (float)(1.0/57.0),  (float)(1.0/79.0),  (float)(1.0/109.0), (float)(1.0/151.0),
        (float)(1.0/209.0), (float)(1.0/289.0), (float)(1.0/399.0), (float)(1.0/552.0),
        (float)(1.0/762.0), (float)(1.0/1052.0),(float)(1.0/1452.0),(float)(1.0/2004.0)};

    float b00 = bounds[0], b01 = bounds[1], b02 = bounds[2], b03 = bounds[3];
    float b10 = bounds[4], b11 = bounds[5], b12 = bounds[6], b13 = bounds[7];

    // verified chain: recip-mult x (f32), recip-mult size (f32)
    float x0 = (p.x - b00) * (1.0f / (b10 - b00));
    float x1 = (p.y - b01) * (1.0f / (b11 - b01));
    float x2 = (p.z - b02) * (1.0f / (b12 - b02));
    float x3 = (p.w - b03) * (1.0f / (b13 - b03));

    int   nm1 = NUMS[l] - 1;
    float invsz = 1.0f / SIZES[l];
    float f0 = x0 * invsz, f1 = x1 * invsz, f2 = x2 * invsz, f3 = x3 * invsz;

    int c0a = min(max((int)f0, 0), nm1), c0b = min(max((int)(f0 + 1.0f), 0), nm1);
    int c1a = min(max((int)f1, 0), nm1), c1b = min(max((int)(f1 + 1.0f), 0), nm1);
    int c2a = min(max((int)f2, 0), nm1), c2b = min(max((int)(f2 + 1.0f), 0), nm1);
    int c3a = min(max((int)f3, 0), nm1), c3b = min(max((int)(f3 + 1.0f), 0), nm1);

    float o0 = f0 - (float)c0a;
    float o1 = f1 - (float)c1a;
    float o2 = f2 - (float)c2a;
    float o3 = f3 - (float)c3a;

    float2 v[16];
    if (l >= 2) {
        const float2* tbl = hasht + (size_t)(l - 2) * HTBL;
        unsigned long long a0 = (unsigned long long)(unsigned int)c0a;
        unsigned long long b0 = (unsigned long long)(unsigned int)c0b;
        unsigned long long t1a = (unsigned long long)(unsigned int)c1a * 19349663ull;
        unsigned long long t1b = (unsigned long long)(unsigned int)c1b * 19349663ull;
        unsigned long long t2a = (unsigned long long)(unsigned int)c2a * 51471207ull;
        unsigned long long t2b = (unsigned long long)(unsigned int)c2b * 51471207ull;
        unsigned long long t3a = (unsigned long long)(unsigned int)c3a * 83492791ull;
        unsigned long long t3b = (unsigned long long)(unsigned int)c3b * 83492791ull;
        bool pair_adj  = (c0b == c0a + 1) && !(c0a & 1);   // h_b = h_a ^ 1, slots {e,e+1}
        bool pair_same = (c0b == c0a);
        #pragma unroll
        for (int k = 0; k < 8; ++k) {
            unsigned long long R = ((k & 1) ? t1b : t1a) ^ ((k & 2) ? t2b : t2a)
                                 ^ ((k & 4) ? t3b : t3a);
            unsigned long long ha = a0 ^ R;
            float2 va, vb;
            if (pair_same) {
                va = tbl[mod_tbl(ha)];
                vb = va;
            } else if (pair_adj) {
                unsigned int m = mod_tbl(ha & ~1ull);       // slot of even member
                bool a_even = !(ha & 1);
                if (m != HTBL - 1 && !(m & 1)) {
                    float4 q = *reinterpret_cast<const float4*>(tbl + m); // 16B aligned
                    va = a_even ? make_float2(q.x, q.y) : make_float2(q.z, q.w);
                    vb = a_even ? make_float2(q.z, q.w) : make_float2(q.x, q.y);
                } else if (m != HTBL - 1) {
                    float2 qa = tbl[m], qb = tbl[m + 1];
                    va = a_even ? qa : qb;
                    vb = a_even ? qb : qa;
                } else {                                    // wrap TBL-1 -> 0
                    va = tbl[a_even ? m : 0];
                    vb = tbl[a_even ? 0 : m];
                }
            } else {
                unsigned long long hb = b0 ^ R;
                va = tbl[mod_tbl(ha)];
                vb = tbl[mod_tbl(hb)];
            }
            v[2 * k]     = va;
            v[2 * k + 1] = vb;
        }
    } else {
        const float2* tbl = dense + (l == 0 ? 0 : 65536);
        int s3 = nm1 + 1, s2 = s3 * s3, s1 = s2 * s3;
        int d0a = c0a * s1, d0b = c0b * s1;
        int d1a = c1a * s2, d1b = c1b * s2;
        int d2a = c2a * s3, d2b = c2b * s3;
        bool adj = (c3b == c3a + 1);
        #pragma unroll
        for (int c = 0; c < 8; ++c) {    // pairs (c, c+8) over dim3: idx, idx+1
            int base = ((c & 1) ? d0b : d0a) + ((c & 2) ? d1b : d1a)
                     + ((c & 4) ? d2b : d2a) + c3a;
            float2 va, vb;
            if (!adj) {
                va = tbl[base]; vb = va;
            } else if (!(base & 1)) {
                float4 q = *reinterpret_cast<const float4*>(tbl + base);
                va = make_float2(q.x, q.y); vb = make_float2(q.z, q.w);
            } else {
                va = tbl[base]; vb = tbl[base + 1];
            }
            v[c]     = va;
            v[c + 8] = vb;
        }
    }

    // f32 weights/accumulation (continuous path; tol 1.1e-3 >> f32 error ~1e-6)
    float w0a = 1.0f - o0, w1a = 1.0f - o1, w2a = 1.0f - o2, w3a = 1.0f - o3;
    float w01[4] = { w0a * w1a, o0 * w1a, w0a * o1, o0 * o1 };
    float ai = 0.0f, aa = 0.0f, ab = 0.0f;
    #pragma unroll
    for (int c = 0; c < 8; ++c) {
        float tri  = w01[c & 3] * ((c & 4) ? o2 : w2a);
        float slo  = v[c].x + v[c].y;          // corner c   (dim3 = a, weight w3a)
        float shi  = v[c + 8].x + v[c + 8].y;  // corner c+8 (dim3 = b, weight o3)
        float tlo  = tri * slo;
        float thi  = tri * shi;
        ai += tlo * w3a + thi * o3;
        aa += tlo;
        ab += thi;
    }
    acc_i = ai; acc_a = aa; acc_b = ab;
}

// Pass 1, phased: blocks [0,4096) run levels 0-7 (one level per XCD under
// round-robin blockIdx%8 -> XCD), blocks [4096,8192) run levels 8-15.
// Per-XCD in-flight table working set ~2.1 MB (+2 MB xyz) ~= L2 capacity.
__global__ __launch_bounds__(256) void gather_kernel(
    const float4* __restrict__ xyz,
    const float2* __restrict__ dense,
    const float2* __restrict__ hasht,
    const float*  __restrict__ bounds,
    float* __restrict__ wsI, float* __restrict__ wsA, float* __restrict__ wsB)
{
    int b = blockIdx.x;
    int phase = b >> 12;                 // 0: levels 0-7, 1: levels 8-15
    int bb = b & 4095;
    int l = (phase << 3) | (bb & 7);
    int n = ((bb >> 3) << 8) + threadIdx.x;
    float4 p = xyz[n];
    float ai, aa, ab;
    compute_point_level(p, bounds, l, ai, aa, ab, dense, hasht);
    wsI[l * NPTS + n] = ai;
    wsA[l * NPTS + n] = aa;
    wsB[l * NPTS + n] = ab;
}

// Pass 2: transpose level-major ws -> row-major out via LDS tiles (64 points/block).
__global__ __launch_bounds__(256) void transpose_kernel(
    const float* __restrict__ wsI, const float* __restrict__ wsA,
    const float* __restrict__ wsB, float* __restrict__ out)
{
    __shared__ float tI[16][65], tA[16][65], tB[16][65];
    int t = threadIdx.x;
    int n0 = blockIdx.x * 64;
    #pragma unroll
    for (int k = 0; k < 4; ++k) {
        int l = k * 4 + (t >> 6);
        int pp = t & 63;
        tI[l][pp] = wsI[l * NPTS + n0 + pp];
        tA[l][pp] = wsA[l * NPTS + n0 + pp];
        tB[l][pp] = wsB[l * NPTS + n0 + pp];
    }
    __syncthreads();
    {
        int pp = t >> 2, q = t & 3;
        float4 v = make_float4(tI[q*4+0][pp], tI[q*4+1][pp], tI[q*4+2][pp], tI[q*4+3][pp]);
        ((float4*)out)[(size_t)(n0 + pp) * 4 + q] = v;
    }
    float4* sm4 = (float4*)(out + (size_t)NPTS * 16);
    #pragma unroll
    for (int j = 0; j < 2; ++j) {
        int idx = j * 256 + t;
        int pp = idx >> 3, q = idx & 7;
        float4 v;
        if (q < 4) v = make_float4(tA[q*4+0][pp], tA[q*4+1][pp], tA[q*4+2][pp], tA[q*4+3][pp]);
        else { int qq = q - 4; v = make_float4(tB[qq*4+0][pp], tB[qq*4+1][pp], tB[qq*4+2][pp], tB[qq*4+3][pp]); }
        sm4[(size_t)(n0 + pp) * 8 + q] = v;
    }
}

// Fallback single-kernel: direct row-major writes.
__global__ __launch_bounds__(256) void embed_kernel(
    const float4* __restrict__ xyz,
    const float2* __restrict__ dense,
    const float2* __restrict__ hasht,
    const float*  __restrict__ bounds,
    float* __restrict__ out)
{
    int tid = blockIdx.x * 256 + threadIdx.x;
    int n = tid >> 4;
    int l = tid & 15;
    float4 p = xyz[n];
    float ai, aa, ab;
    compute_point_level(p, bounds, l, ai, aa, ab, dense, hasht);
    out[n * 16 + l] = ai;
    float* sm = out + NPTS * 16;
    sm[n * 32 + l]      = aa;
    sm[n * 32 + 16 + l] = ab;
}

extern "C" void kernel_launch(void* const* d_in, const int* in_sizes, int n_in,
                              void* d_out, int out_size, void* d_ws, size_t ws_size,
                              hipStream_t stream) {
    const float4* xyz    = (const float4*)d_in[0];
    const float2* dense  = (const float2*)d_in[1];
    const float2* hasht  = (const float2*)d_in[2];
    const float*  bounds = (const float*)d_in[3];
    float* out = (float*)d_out;

    const size_t plane = (size_t)16 * NPTS;
    if (ws_size >= 3 * plane * sizeof(float)) {
        float* wsI = (float*)d_ws;
        float* wsA = wsI + plane;
        float* wsB = wsA + plane;
        gather_kernel<<<dim3(8192), dim3(256), 0, stream>>>(xyz, dense, hasht, bounds, wsI, wsA, wsB);
        transpose_kernel<<<dim3(NPTS / 64), dim3(256), 0, stream>>>(wsI, wsA, wsB, out);
    } else {
        embed_kernel<<<dim3((NPTS * 16) / 256), dim3(256), 0, stream>>>(xyz, dense, hasht, bounds, out);
    }
}

// Round 16
// 108.527 us; speedup vs baseline: 2.8198x; 1.0060x over previous
//
#include <hip/hip_runtime.h>

#define NPTS 131072
#define HTBL 262147

__device__ __forceinline__ unsigned int mod_tbl(unsigned long long h) {
    int r = (int)((unsigned int)h & 0x3FFFFu) - 3 * (int)(unsigned int)(h >> 18) + 3145764;
    int s = (r & 0x3FFFF) - 3 * (r >> 18);
    return (unsigned int)(s < 0 ? s + HTBL : s);
}

__constant__ int   cNUMS[16]  = {16,22,30,42,58,80,110,152,210,290,400,553,763,1053,1453,2005};

__device__ __forceinline__ void corners_offsets(
    float4 p, float b00,float b01,float b02,float b03,
    float b10,float b11,float b12,float b13,
    int nm1, float invsz,
    int C[8], float o[4])
{
    // verified chain: recip-mult x (f32), recip-mult size (f32)
    float x0 = (p.x - b00) * (1.0f / (b10 - b00));
    float x1 = (p.y - b01) * (1.0f / (b11 - b01));
    float x2 = (p.z - b02) * (1.0f / (b12 - b02));
    float x3 = (p.w - b03) * (1.0f / (b13 - b03));
    float f0 = x0 * invsz, f1 = x1 * invsz, f2 = x2 * invsz, f3 = x3 * invsz;
    C[0] = min(max((int)f0, 0), nm1); C[1] = min(max((int)(f0 + 1.0f), 0), nm1);
    C[2] = min(max((int)f1, 0), nm1); C[3] = min(max((int)(f1 + 1.0f), 0), nm1);
    C[4] = min(max((int)f2, 0), nm1); C[5] = min(max((int)(f2 + 1.0f), 0), nm1);
    C[6] = min(max((int)f3, 0), nm1); C[7] = min(max((int)(f3 + 1.0f), 0), nm1);
    o[0] = f0 - (float)C[0];
    o[1] = f1 - (float)C[2];
    o[2] = f2 - (float)C[4];
    o[3] = f3 - (float)C[6];
}

__device__ __forceinline__ void gather_hash(
    const float2* __restrict__ tbl, const int C[8], float2 v[16])
{
    unsigned long long a0  = (unsigned long long)(unsigned int)C[0];
    unsigned long long b0  = (unsigned long long)(unsigned int)C[1];
    unsigned long long t1a = (unsigned long long)(unsigned int)C[2] * 19349663ull;
    unsigned long long t1b = (unsigned long long)(unsigned int)C[3] * 19349663ull;
    unsigned long long t2a = (unsigned long long)(unsigned int)C[4] * 51471207ull;
    unsigned long long t2b = (unsigned long long)(unsigned int)C[5] * 51471207ull;
    unsigned long long t3a = (unsigned long long)(unsigned int)C[6] * 83492791ull;
    unsigned long long t3b = (unsigned long long)(unsigned int)C[7] * 83492791ull;
    bool pair_adj  = (C[1] == C[0] + 1) && !(C[0] & 1);
    bool pair_same = (C[1] == C[0]);
    #pragma unroll
    for (int k = 0; k < 8; ++k) {
        unsigned long long R = ((k & 1) ? t1b : t1a) ^ ((k & 2) ? t2b : t2a)
                             ^ ((k & 4) ? t3b : t3a);
        unsigned long long ha = a0 ^ R;
        float2 va, vb;
        if (pair_same) {
            va = tbl[mod_tbl(ha)];
            vb = va;
        } else if (pair_adj) {
            unsigned int m = mod_tbl(ha & ~1ull);
            bool a_even = !(ha & 1);
            if (m != HTBL - 1 && !(m & 1)) {
                float4 q = *reinterpret_cast<const float4*>(tbl + m);
                va = a_even ? make_float2(q.x, q.y) : make_float2(q.z, q.w);
                vb = a_even ? make_float2(q.z, q.w) : make_float2(q.x, q.y);
            } else if (m != HTBL - 1) {
                float2 qa = tbl[m], qb = tbl[m + 1];
                va = a_even ? qa : qb;
                vb = a_even ? qb : qa;
            } else {
                va = tbl[a_even ? m : 0];
                vb = tbl[a_even ? 0 : m];
            }
        } else {
            unsigned long long hb = b0 ^ R;
            va = tbl[mod_tbl(ha)];
            vb = tbl[mod_tbl(hb)];
        }
        v[2 * k]     = va;
        v[2 * k + 1] = vb;
    }
}

__device__ __forceinline__ void gather_dense(
    const float2* __restrict__ tbl, const int C[8], int nm1, float2 v[16])
{
    int s3 = nm1 + 1, s2 = s3 * s3, s1 = s2 * s3;
    int d0a = C[0] * s1, d0b = C[1] * s1;
    int d1a = C[2] * s2, d1b = C[3] * s2;
    int d2a = C[4] * s3, d2b = C[5] * s3;
    bool adj = (C[7] == C[6] + 1);
    #pragma unroll
    for (int c = 0; c < 8; ++c) {
        int base = ((c & 1) ? d0b : d0a) + ((c & 2) ? d1b : d1a)
                 + ((c & 4) ? d2b : d2a) + C[6];
        float2 va, vb;
        if (!adj) {
            va = tbl[base]; vb = va;
        } else if (!(base & 1)) {
            float4 q = *reinterpret_cast<const float4*>(tbl + base);
            va = make_float2(q.x, q.y); vb = make_float2(q.z, q.w);
        } else {
            va = tbl[base]; vb = tbl[base + 1];
        }
        v[c]     = va;
        v[c + 8] = vb;
    }
}

__device__ __forceinline__ void accumulate(
    const float2 v[16], const float o[4],
    float& acc_i, float& acc_a, float& acc_b)
{
    float w0a = 1.0f - o[0], w1a = 1.0f - o[1], w2a = 1.0f - o[2], w3a = 1.0f - o[3];
    float w01[4] = { w0a * w1a, o[0] * w1a, w0a * o[1], o[0] * o[1] };
    float ai = 0.0f, aa = 0.0f, ab = 0.0f;
    #pragma unroll
    for (int c = 0; c < 8; ++c) {
        float tri = w01[c & 3] * ((c & 4) ? o[2] : w2a);
        float tlo = tri * (v[c].x + v[c].y);
        float thi = tri * (v[c + 8].x + v[c + 8].y);
        ai += tlo * w3a + thi * o[3];
        aa += tlo;
        ab += thi;
    }
    acc_i = ai; acc_a = aa; acc_b = ab;
}

// Pass 1: 2 points/thread, level-per-block, phased (levels 0-7 then 8-15) so each
// XCD's in-flight table set ~2.1 MB fits L2. All 32 gathers issued before use.
__global__ __launch_bounds__(256) void gather_kernel2(
    const float4* __restrict__ xyz,
    const float2* __restrict__ dense,
    const float2* __restrict__ hasht,
    const float*  __restrict__ bounds,
    float* __restrict__ wsI, float* __restrict__ wsA, float* __restrict__ wsB)
{
    const float FSIZES[16] = {
        (float)(1.0/15.0),  (float)(1.0/21.0),  (float)(1.0/29.0),  (float)(1.0/41.0),
        (float)(1.0/57.0),  (float)(1.0/79.0),  (float)(1.0/109.0), (float)(1.0/151.0),
        (float)(1.0/209.0), (float)(1.0/289.0), (float)(1.0/399.0), (float)(1.0/552.0),
        (float)(1.0/762.0), (float)(1.0/1052.0),(float)(1.0/1452.0),(float)(1.0/2004.0)};

    int b = blockIdx.x;
    int phase = b >> 11;                  // 0: levels 0-7, 1: levels 8-15
    int bb = b & 2047;
    int l = (phase << 3) | (bb & 7);      // low 3 bits of blockIdx -> XCD
    int n0 = ((bb >> 3) << 9) + threadIdx.x;

    float4 P0 = xyz[n0];
    float4 P1 = xyz[n0 + 256];

    float b00 = bounds[0], b01 = bounds[1], b02 = bounds[2], b03 = bounds[3];
    float b10 = bounds[4], b11 = bounds[5], b12 = bounds[6], b13 = bounds[7];
    int   nm1 = cNUMS[l] - 1;
    float invsz = 1.0f / FSIZES[l];

    int   C0[8], C1[8];
    float o0v[4], o1v[4];
    corners_offsets(P0, b00,b01,b02,b03, b10,b11,b12,b13, nm1, invsz, C0, o0v);
    corners_offsets(P1, b00,b01,b02,b03, b10,b11,b12,b13, nm1, invsz, C1, o1v);

    float2 v0[16], v1[16];
    if (l >= 2) {
        const float2* tbl = hasht + (size_t)(l - 2) * HTBL;
        gather_hash(tbl, C0, v0);
        gather_hash(tbl, C1, v1);
    } else {
        const float2* tbl = dense + (l == 0 ? 0 : 65536);
        gather_dense(tbl, C0, nm1, v0);
        gather_dense(tbl, C1, nm1, v1);
    }

    float ai0, aa0, ab0, ai1, aa1, ab1;
    accumulate(v0, o0v, ai0, aa0, ab0);
    accumulate(v1, o1v, ai1, aa1, ab1);

    wsI[l * NPTS + n0] = ai0;  wsI[l * NPTS + n0 + 256] = ai1;
    wsA[l * NPTS + n0] = aa0;  wsA[l * NPTS + n0 + 256] = aa1;
    wsB[l * NPTS + n0] = ab0;  wsB[l * NPTS + n0 + 256] = ab1;
}

// Pass 2: transpose level-major ws -> row-major out via LDS tiles (64 points/block).
__global__ __launch_bounds__(256) void transpose_kernel(
    const float* __restrict__ wsI, const float* __restrict__ wsA,
    const float* __restrict__ wsB, float* __restrict__ out)
{
    __shared__ float tI[16][65], tA[16][65], tB[16][65];
    int t = threadIdx.x;
    int n0 = blockIdx.x * 64;
    #pragma unroll
    for (int k = 0; k < 4; ++k) {
        int l = k * 4 + (t >> 6);
        int pp = t & 63;
        tI[l][pp] = wsI[l * NPTS + n0 + pp];
        tA[l][pp] = wsA[l * NPTS + n0 + pp];
        tB[l][pp] = wsB[l * NPTS + n0 + pp];
    }
    __syncthreads();
    {
        int pp = t >> 2, q = t & 3;
        float4 v = make_float4(tI[q*4+0][pp], tI[q*4+1][pp], tI[q*4+2][pp], tI[q*4+3][pp]);
        ((float4*)out)[(size_t)(n0 + pp) * 4 + q] = v;
    }
    float4* sm4 = (float4*)(out + (size_t)NPTS * 16);
    #pragma unroll
    for (int j = 0; j < 2; ++j) {
        int idx = j * 256 + t;
        int pp = idx >> 3, q = idx & 7;
        float4 v;
        if (q < 4) v = make_float4(tA[q*4+0][pp], tA[q*4+1][pp], tA[q*4+2][pp], tA[q*4+3][pp]);
        else { int qq = q - 4; v = make_float4(tB[qq*4+0][pp], tB[qq*4+1][pp], tB[qq*4+2][pp], tB[qq*4+3][pp]); }
        sm4[(size_t)(n0 + pp) * 8 + q] = v;
    }
}

// Fallback single-kernel: direct row-major writes (passing r12 path).
__global__ __launch_bounds__(256) void embed_kernel(
    const float4* __restrict__ xyz,
    const float2* __restrict__ dense,
    const float2* __restrict__ hasht,
    const float*  __restrict__ bounds,
    float* __restrict__ out)
{
    const float FSIZES[16] = {
        (float)(1.0/15.0),  (float)(1.0/21.0),  (float)(1.0/29.0),  (float)(1.0/41.0),
        (float)(1.0/57.0),  (float)(1.0/79.0),  (float)(1.0/109.0), (float)(1.0/151.0),
        (float)(1.0/209.0), (float)(1.0/289.0), (float)(1.0/399.0), (float)(1.0/552.0),
        (float)(1.0/762.0), (float)(1.0/1052.0),(float)(1.0/1452.0),(float)(1.0/2004.0)};
    int tid = blockIdx.x * 256 + threadIdx.x;
    int n = tid >> 4;
    int l = tid & 15;
    float4 p = xyz[n];
    float b00 = bounds[0], b01 = bounds[1], b02 = bounds[2], b03 = bounds[3];
    float b10 = bounds[4], b11 = bounds[5], b12 = bounds[6], b13 = bounds[7];
    int   nm1 = cNUMS[l] - 1;
    float invsz = 1.0f / FSIZES[l];
    int C[8]; float o[4];
    corners_offsets(p, b00,b01,b02,b03, b10,b11,b12,b13, nm1, invsz, C, o);
    float2 v[16];
    if (l >= 2) gather_hash(hasht + (size_t)(l - 2) * HTBL, C, v);
    else        gather_dense(dense + (l == 0 ? 0 : 65536), C, nm1, v);
    float ai, aa, ab;
    accumulate(v, o, ai, aa, ab);
    out[n * 16 + l] = ai;
    float* sm = out + NPTS * 16;
    sm[n * 32 + l]      = aa;
    sm[n * 32 + 16 + l] = ab;
}

extern "C" void kernel_launch(void* const* d_in, const int* in_sizes, int n_in,
                              void* d_out, int out_size, void* d_ws, size_t ws_size,
                              hipStream_t stream) {
    const float4* xyz    = (const float4*)d_in[0];
    const float2* dense  = (const float2*)d_in[1];
    const float2* hasht  = (const float2*)d_in[2];
    const float*  bounds = (const float*)d_in[3];
    float* out = (float*)d_out;

    const size_t plane = (size_t)16 * NPTS;
    if (ws_size >= 3 * plane * sizeof(float)) {
        float* wsI = (float*)d_ws;
        float* wsA = wsI + plane;
        float* wsB = wsA + plane;
        gather_kernel2<<<dim3(4096), dim3(256), 0, stream>>>(xyz, dense, hasht, bounds, wsI, wsA, wsB);
        transpose_kernel<<<dim3(NPTS / 64), dim3(256), 0, stream>>>(wsI, wsA, wsB, out);
    } else {
        embed_kernel<<<dim3((NPTS * 16) / 256), dim3(256), 0, stream>>>(xyz, dense, hasht, bounds, out);
    }
}